// Round 2
// baseline (1524.458 us; speedup 1.0000x reference)
//
#include <hip/hip_runtime.h>

#define NTOK   8192
#define DMODEL 1024
#define NATOM  16384

typedef _Float16 half8  __attribute__((ext_vector_type(8)));
typedef _Float16 half4_t __attribute__((ext_vector_type(4)));
typedef float    f32x4  __attribute__((ext_vector_type(4)));

// async global->LDS, 16B per lane; LDS dest is wave-uniform base + lane*16
#define GLOAD_LDS16(gsrc, ldst) \
  __builtin_amdgcn_global_load_lds((const __attribute__((address_space(1))) unsigned int*)(gsrc), \
                                   (__attribute__((address_space(3))) unsigned int*)(ldst), 16, 0, 0)

// ---------------- prep: fp32 -> fp16 (x only) ----------------
__global__ void cvt_f32_f16(const float* __restrict__ in, _Float16* __restrict__ out, int n4) {
  int i = blockIdx.x * 256 + threadIdx.x;
  if (i >= n4) return;
  float4 v = ((const float4*)in)[i];
  half4_t h;
  h[0] = (_Float16)v.x; h[1] = (_Float16)v.y; h[2] = (_Float16)v.z; h[3] = (_Float16)v.w;
  ((half4_t*)out)[i] = h;
}

// ---------------- prep: dict f32 -> Dh [16384,1024] f16 AND dT [1024,16384] f16 ----------------
__global__ void transpose_dict(const float* __restrict__ dict,
                               _Float16* __restrict__ Dh, _Float16* __restrict__ dT) {
  __shared__ _Float16 tile[64][68];
  int a0 = blockIdx.x * 64;   // atom tile
  int d0 = blockIdx.y * 64;   // dim tile
  int tid = threadIdx.x;
  int c = tid & 63;
  int r0 = tid >> 6;
  #pragma unroll
  for (int i = 0; i < 16; i++) {
    int r = r0 + i * 4;
    _Float16 h = (_Float16)dict[(size_t)(a0 + r) * DMODEL + d0 + c];
    tile[r][c] = h;
    Dh[(size_t)(a0 + r) * DMODEL + d0 + c] = h;
  }
  __syncthreads();
  #pragma unroll
  for (int i = 0; i < 16; i++) {
    int rd = r0 + i * 4;
    dT[(size_t)(d0 + rd) * NATOM + a0 + c] = tile[c][rd];
  }
}

__global__ void zero_lsum(float* __restrict__ lsum) {
  lsum[blockIdx.x * 256 + threadIdx.x] = 0.0f;
}

// staging helper: 128 rows x 32 k, XOR k-chunk swizzle on the global source side.
// Per wave: exactly 4 global_load_lds instructions (vmcnt += 4 per call).
__device__ __forceinline__ void stage_ab(const _Float16* __restrict__ A,
                                         const _Float16* __restrict__ B,
                                         _Float16* As, _Float16* Bs,
                                         size_t arow0, size_t brow0, size_t ldk,
                                         int k0, int tid) {
  #pragma unroll
  for (int i = 0; i < 2; i++) {
    int L = tid + i * 256;               // 0..511 = 128 rows x 4 chunks
    int r = L >> 2, pc = L & 3;
    int c = pc ^ ((r >> 1) & 3);
    GLOAD_LDS16(A + (arow0 + r) * ldk + k0 + c * 8, As + (size_t)L * 8);
    GLOAD_LDS16(B + (brow0 + r) * ldk + k0 + c * 8, Bs + (size_t)L * 8);
  }
}

// ---------------- kernel 1: E = mask ? exp(x @ dict^T) : 0, + row-tile sum/max ----------------
// 128x128 tile, BK=32, TRIPLE-buffered staging (3 x 16KB = 48KB LDS -> 3 blocks/CU),
// counted vmcnt: phase t consumes buf[t%3], stages tile t+2 into buf[(t+2)%3] (which was
// consumed at phase t-1; the barrier at top of phase t makes that reuse safe). Steady-state
// wait is vmcnt(4) — only the final phase drains to 0. Grid is the PROVEN 2D mapping
// (bx=atom tile, by=token tile): round-robin dispatch gives each XCD a fixed 4MB Dh
// working set that exactly fits its private L2 (round-1's flat swizzle broke this:
// FETCH 806MB -> 1.32GB).
__launch_bounds__(256, 3)
__global__ void score_kernel(const _Float16* __restrict__ Xh,
                             const _Float16* __restrict__ Dh,
                             const int* __restrict__ mask,
                             _Float16* __restrict__ E,
                             float* __restrict__ lsum,
                             _Float16* __restrict__ Tmax) {   // [128 tiles][8192 tokens]
  __shared__ _Float16 lds[24576];          // 3 bufs x (As 4096 + Bs 4096); epilogue reuses 128x136
  const int tid  = threadIdx.x;
  const int lane = tid & 63;
  const int wave = tid >> 6;
  const int wm = wave >> 1, wn = wave & 1;
  const int m0 = blockIdx.y * 128;         // token tile
  const int n0 = blockIdx.x * 128;         // atom tile

  const int frow = lane & 15;
  const int fkc  = lane >> 4;

  f32x4 acc[4][4] = {};

  // prologue: stage tiles 0,1 -> 8 loads/wave in flight
  stage_ab(Xh, Dh, lds,        lds + 4096,  m0, n0, DMODEL, 0,  tid);
  stage_ab(Xh, Dh, lds + 8192, lds + 12288, m0, n0, DMODEL, 32, tid);

  for (int t = 0; t < 32; ++t) {
    // entering phase t: {tile t, tile t+1} outstanding (<=8); wait until tile t's 4 retire
    if (t < 31) asm volatile("s_waitcnt vmcnt(4)" ::: "memory");
    else        asm volatile("s_waitcnt vmcnt(0)" ::: "memory");
    __builtin_amdgcn_s_barrier();
    __builtin_amdgcn_sched_barrier(0);     // nothing hoists above the barrier
    const int b = t % 3;
    const _Float16* As = lds + b * 8192;
    const _Float16* Bs = As + 4096;
    half8 af[4], bf[4];
    #pragma unroll
    for (int i = 0; i < 4; i++) {
      int ar = wm * 64 + i * 16 + frow;
      int br = wn * 64 + i * 16 + frow;
      af[i] = *(const half8*)&As[ar * 32 + ((fkc ^ ((ar >> 1) & 3)) << 3)];
      bf[i] = *(const half8*)&Bs[br * 32 + ((fkc ^ ((br >> 1) & 3)) << 3)];
    }
    if (t + 2 < 32) {
      int nb = (t + 2) % 3;                // buffer consumed at phase t-1: barrier-safe
      stage_ab(Xh, Dh, lds + nb * 8192, lds + nb * 8192 + 4096, m0, n0, DMODEL, (t + 2) * 32, tid);
    }
    __builtin_amdgcn_s_setprio(1);
    #pragma unroll
    for (int i = 0; i < 4; i++)
      #pragma unroll
      for (int j = 0; j < 4; j++)
        acc[i][j] = __builtin_amdgcn_mfma_f32_16x16x32_f16(af[i], bf[j], acc[i][j], 0, 0, 0);
    __builtin_amdgcn_s_setprio(0);
    __builtin_amdgcn_sched_barrier(0);     // pin reads+lgkm+MFMA inside the phase
  }

  __syncthreads();
  // epilogue: C/D layout col=lane&15, row=(lane>>4)*4+reg. mask+exp -> LDS (stride 136) -> stores.
  const int cr = (lane >> 4) * 4;
  const int cc = lane & 15;
  #pragma unroll
  for (int i = 0; i < 4; i++) {
    #pragma unroll
    for (int j = 0; j < 4; j++) {
      #pragma unroll
      for (int r = 0; r < 4; r++) {
        int lr = wm * 64 + i * 16 + cr + r;
        int lc = wn * 64 + j * 16 + cc;
        int mk = mask[(size_t)(m0 + lr) * NATOM + (n0 + lc)];
        float e = mk ? __expf(acc[i][j][r]) : 0.0f;   // scores bounded |s|<=11: no max-subtract
        lds[lr * 136 + lc] = (_Float16)e;
      }
    }
  }
  __syncthreads();
  // coalesced E store
  #pragma unroll
  for (int i = 0; i < 8; i++) {
    int chunk = i * 256 + tid;
    int r  = chunk >> 4;
    int c8 = (chunk & 15) * 8;
    *(half8*)&E[(size_t)(m0 + r) * NATOM + n0 + c8] = *(const half8*)&lds[r * 136 + c8];
  }
  // per-row partial sum (-> atomic lsum) and tile max (-> Tmax, tile-major for coalesced store)
  {
    int r = tid >> 1, h = tid & 1;
    const _Float16* rowp = &lds[r * 136 + h * 64];
    float s = 0.0f, m = 0.0f;
    #pragma unroll
    for (int i = 0; i < 8; i++) {
      half8 v = *(const half8*)&rowp[i * 8];
      #pragma unroll
      for (int j = 0; j < 8; j++) { float f = (float)v[j]; s += f; m = fmaxf(m, f); }
    }
    s += __shfl_xor(s, 1, 64);
    m = fmaxf(m, __shfl_xor(m, 1, 64));
    if (h == 0) {
      atomicAdd(&lsum[m0 + r], s);
      Tmax[(size_t)blockIdx.x * NTOK + m0 + r] = (_Float16)m;
    }
  }
}

// ---------------- kernel 2: sparse argmax scan (1 wave / token) ----------------
__global__ void scan_lite(const _Float16* __restrict__ E,
                          const _Float16* __restrict__ Tmax,
                          const float* __restrict__ x,
                          const float* __restrict__ dict,
                          float* __restrict__ argout) {
  const int t = blockIdx.x;
  const int lane = threadIdx.x;            // 0..63
  float m0 = (float)Tmax[(size_t)lane * NTOK + t];
  float m1 = (float)Tmax[(size_t)(64 + lane) * NTOK + t];
  float mx = fmaxf(m0, m1);
  #pragma unroll
  for (int off = 32; off > 0; off >>= 1) mx = fmaxf(mx, __shfl_xor(mx, off, 64));

  __shared__ int cnt;
  __shared__ int cand[32];
  __shared__ double csc[32];
  if (lane == 0) cnt = 0;
  __syncthreads();

  if (mx > 0.0f) {
    float thr = 0.98f * mx;
    unsigned long long q0 = __ballot(m0 >= thr);
    unsigned long long q1 = __ballot(m1 >= thr);
    while (q0 | q1) {
      int tile;
      if (q0) { tile = __ffsll(q0) - 1; q0 &= q0 - 1; }
      else    { tile = 64 + __ffsll(q1) - 1; q1 &= q1 - 1; }
      const _Float16* ep = E + (size_t)t * NATOM + tile * 128;
      float e0 = (float)ep[lane], e1 = (float)ep[64 + lane];
      if (e0 >= thr) { int p = atomicAdd(&cnt, 1); if (p < 32) cand[p] = tile * 128 + lane; }
      if (e1 >= thr) { int p = atomicAdd(&cnt, 1); if (p < 32) cand[p] = tile * 128 + 64 + lane; }
    }
  }
  __syncthreads();
  int nc = min(cnt, 32);
  const float* xr = x + (size_t)t * DMODEL;
  for (int c = 0; c < nc; c++) {
    const float* dr = dict + (size_t)cand[c] * DMODEL;
    double a = 0.0;
    #pragma unroll
    for (int i = 0; i < 16; i++) {
      int d = lane + i * 64;
      a += (double)xr[d] * (double)dr[d];
    }
    #pragma unroll
    for (int off = 32; off > 0; off >>= 1) a += __shfl_down(a, off, 64);
    if (lane == 0) csc[c] = a;
  }
  __syncthreads();
  if (lane == 0) {
    int best = 0;                          // all-masked -> np.argmax of equal values = 0
    if (nc > 0) {
      double bs = -1e300;
      best = NATOM;
      for (int c = 0; c < nc; c++)
        if (csc[c] > bs || (csc[c] == bs && cand[c] < best)) { bs = csc[c]; best = cand[c]; }
    }
    argout[t] = (float)best;               // harness reads d_out as float32
  }
}

// ---------------- kernel 3: recon = (E @ dT^T) / l ----------------
// M64 x N128, K=16384 (512 tiles). Grid 1024 = 4 blocks/CU (36KB LDS, triple-buffered,
// 3 loads/wave/stage -> steady-state vmcnt(3)). XCD-clustered mapping: XCD k owns m-tiles
// [16k,16k+16) x all 8 n-tiles, so each 2MB E panel is fetched once into the XCD L2 and
// shared by its 8 co-resident n-blocks; per-XCD stream = 32MB E + 32MB DT.
__launch_bounds__(256, 4)
__global__ void recon_kernel(const _Float16* __restrict__ E,
                             const _Float16* __restrict__ DT,
                             const float* __restrict__ lsum,
                             float* __restrict__ out) {
  __shared__ _Float16 lds[18432];          // 3 bufs x (As 64x32 = 2048 + Bs 128x32 = 4096)
  const int tid  = threadIdx.x;
  const int lane = tid & 63;
  const int wave = tid >> 6;
  const int wm = wave >> 1, wn = wave & 1;
  const int bid = blockIdx.x;
  const int xcd = bid & 7;
  const int idx = bid >> 3;                // 0..127
  const int mt  = xcd * 16 + (idx & 15);   // m-tile 0..127, clustered per XCD
  const int nt  = idx >> 4;                // n-tile 0..7
  const int m0 = mt * 64;
  const int n0 = nt * 128;

  const int frow = lane & 15;
  const int fkc  = lane >> 4;

  f32x4 acc[2][4] = {};

  auto stage = [&](int k0, int b) {
    _Float16* As = lds + b * 6144;
    _Float16* Bs = As + 2048;
    {
      int L = tid;                         // 64 rows x 4 chunks
      int r = L >> 2, pc = L & 3;
      int c = pc ^ ((r >> 1) & 3);
      GLOAD_LDS16(E + (size_t)(m0 + r) * NATOM + k0 + c * 8, As + (size_t)L * 8);
    }
    #pragma unroll
    for (int i = 0; i < 2; i++) {
      int L = tid + i * 256;               // 128 rows x 4 chunks
      int r = L >> 2, pc = L & 3;
      int c = pc ^ ((r >> 1) & 3);
      GLOAD_LDS16(DT + (size_t)(n0 + r) * NATOM + k0 + c * 8, Bs + (size_t)L * 8);
    }
  };

  stage(0, 0);
  stage(32, 1);

  for (int t = 0; t < 512; ++t) {
    if (t < 511) asm volatile("s_waitcnt vmcnt(3)" ::: "memory");
    else         asm volatile("s_waitcnt vmcnt(0)" ::: "memory");
    __builtin_amdgcn_s_barrier();
    __builtin_amdgcn_sched_barrier(0);
    const int b = t % 3;
    const _Float16* As = lds + b * 6144;
    const _Float16* Bs = As + 2048;
    half8 af[2], bf[4];
    #pragma unroll
    for (int i = 0; i < 2; i++) {
      int ar = wm * 32 + i * 16 + frow;
      af[i] = *(const half8*)&As[ar * 32 + ((fkc ^ ((ar >> 1) & 3)) << 3)];
    }
    #pragma unroll
    for (int j = 0; j < 4; j++) {
      int br = wn * 64 + j * 16 + frow;
      bf[j] = *(const half8*)&Bs[br * 32 + ((fkc ^ ((br >> 1) & 3)) << 3)];
    }
    if (t + 2 < 512) stage((t + 2) * 32, (t + 2) % 3);
    __builtin_amdgcn_s_setprio(1);
    #pragma unroll
    for (int i = 0; i < 2; i++)
      #pragma unroll
      for (int j = 0; j < 4; j++)
        acc[i][j] = __builtin_amdgcn_mfma_f32_16x16x32_f16(af[i], bf[j], acc[i][j], 0, 0, 0);
    __builtin_amdgcn_s_setprio(0);
    __builtin_amdgcn_sched_barrier(0);
  }

  const int cr = (lane >> 4) * 4;
  const int cc = lane & 15;
  #pragma unroll
  for (int i = 0; i < 2; i++) {
    #pragma unroll
    for (int r = 0; r < 4; r++) {
      int lr = wm * 32 + i * 16 + cr + r;
      float sc = 1.0f / lsum[m0 + lr];
      #pragma unroll
      for (int j = 0; j < 4; j++) {
        int lc = wn * 64 + j * 16 + cc;
        out[(size_t)(m0 + lr) * DMODEL + (n0 + lc)] = acc[i][j][r] * sc;
      }
    }
  }
}

extern "C" void kernel_launch(void* const* d_in, const int* in_sizes, int n_in,
                              void* d_out, int out_size, void* d_ws, size_t ws_size,
                              hipStream_t stream) {
  const float* x    = (const float*)d_in[0];
  const float* dict = (const float*)d_in[1];
  const int*   mask = (const int*)d_in[2];
  float* recon  = (float*)d_out;
  float* argout = recon + (size_t)NTOK * DMODEL;

  // workspace layout (336 MB + 32 KB — proven size)
  char* w = (char*)d_ws;
  _Float16* Xh = (_Float16*)(w);                                 // 16 MB  [8192,1024]
  _Float16* Dh = (_Float16*)(w + (size_t)16  * 1024 * 1024);     // 32 MB  [16384,1024]
  _Float16* DT = (_Float16*)(w + (size_t)48  * 1024 * 1024);     // 32 MB  [1024,16384]
  _Float16* E  = (_Float16*)(w + (size_t)80  * 1024 * 1024);     // 256 MB [8192,16384]
  float*  lsum = (float*)  (w + (size_t)336 * 1024 * 1024);      // 32 KB
  // Tmax (2 MB fp16) borrows the front of d_out's recon region; scan_lite consumes it
  // before recon_kernel overwrites the region (stream-serialized).
  _Float16* Tmax = (_Float16*)d_out;                             // [128][8192]

  cvt_f32_f16<<<dim3(NTOK * DMODEL / 4 / 256), 256, 0, stream>>>(x, Xh, NTOK * DMODEL / 4);
  transpose_dict<<<dim3(NATOM / 64, DMODEL / 64), 256, 0, stream>>>(dict, Dh, DT);
  zero_lsum<<<dim3(NTOK / 256), 256, 0, stream>>>(lsum);
  score_kernel<<<dim3(NATOM / 128, NTOK / 128), 256, 0, stream>>>(Xh, Dh, mask, E, lsum, Tmax);
  scan_lite<<<dim3(NTOK), 64, 0, stream>>>(E, Tmax, x, dict, argout);
  recon_kernel<<<dim3(1024), 256, 0, stream>>>(E, DT, lsum, recon);
}

// Round 3
// 1426.172 us; speedup vs baseline: 1.0689x; 1.0689x over previous
//
#include <hip/hip_runtime.h>

#define NTOK   8192
#define DMODEL 1024
#define NATOM  16384

typedef _Float16 half8  __attribute__((ext_vector_type(8)));
typedef _Float16 half4_t __attribute__((ext_vector_type(4)));
typedef float    f32x4  __attribute__((ext_vector_type(4)));

// async global->LDS, 16B per lane; LDS dest is wave-uniform base + lane*16
#define GLOAD_LDS16(gsrc, ldst) \
  __builtin_amdgcn_global_load_lds((const __attribute__((address_space(1))) unsigned int*)(gsrc), \
                                   (__attribute__((address_space(3))) unsigned int*)(ldst), 16, 0, 0)

// ---------------- prep: fp32 -> fp16 (x only) ----------------
__global__ void cvt_f32_f16(const float* __restrict__ in, _Float16* __restrict__ out, int n4) {
  int i = blockIdx.x * 256 + threadIdx.x;
  if (i >= n4) return;
  float4 v = ((const float4*)in)[i];
  half4_t h;
  h[0] = (_Float16)v.x; h[1] = (_Float16)v.y; h[2] = (_Float16)v.z; h[3] = (_Float16)v.w;
  ((half4_t*)out)[i] = h;
}

// ---------------- prep: dict f32 -> Dh [16384,1024] f16 AND dT [1024,16384] f16 ----------------
__global__ void transpose_dict(const float* __restrict__ dict,
                               _Float16* __restrict__ Dh, _Float16* __restrict__ dT) {
  __shared__ _Float16 tile[64][68];
  int a0 = blockIdx.x * 64;   // atom tile
  int d0 = blockIdx.y * 64;   // dim tile
  int tid = threadIdx.x;
  int c = tid & 63;
  int r0 = tid >> 6;
  #pragma unroll
  for (int i = 0; i < 16; i++) {
    int r = r0 + i * 4;
    _Float16 h = (_Float16)dict[(size_t)(a0 + r) * DMODEL + d0 + c];
    tile[r][c] = h;
    Dh[(size_t)(a0 + r) * DMODEL + d0 + c] = h;
  }
  __syncthreads();
  #pragma unroll
  for (int i = 0; i < 16; i++) {
    int rd = r0 + i * 4;
    dT[(size_t)(d0 + rd) * NATOM + a0 + c] = tile[c][rd];
  }
}

__global__ void zero_lsum(float* __restrict__ lsum) {
  lsum[blockIdx.x * 256 + threadIdx.x] = 0.0f;
}

// staging helper: 128 rows x 32 k, XOR k-chunk swizzle on the global source side
__device__ __forceinline__ void stage_ab(const _Float16* __restrict__ A,
                                         const _Float16* __restrict__ B,
                                         _Float16* As, _Float16* Bs,
                                         size_t arow0, size_t brow0, size_t ldk,
                                         int k0, int tid) {
  #pragma unroll
  for (int i = 0; i < 2; i++) {
    int L = tid + i * 256;               // 0..511 = 128 rows x 4 chunks
    int r = L >> 2, pc = L & 3;
    int c = pc ^ ((r >> 1) & 3);
    GLOAD_LDS16(A + (arow0 + r) * ldk + k0 + c * 8, As + (size_t)L * 8);
    GLOAD_LDS16(B + (brow0 + r) * ldk + k0 + c * 8, Bs + (size_t)L * 8);
  }
}

// ---------------- kernel 1: E = mask ? exp(x @ dict^T) : 0, + row-tile sum/max ----------------
// ROUND-0 VERBATIM (best measured: 456 us): 128x128 tile, BK=32, 2-phase double-buffer,
// __syncthreads per phase, 34KB LDS -> 4 blocks/CU. Proven 2D grid (bx=atom,by=token):
// round-robin dispatch gives each XCD a recurring 4MB Dh working set fitting its L2.
// Only change: Tmax store is now TOKEN-MAJOR [8192][128] for scan_lite coalescing.
__launch_bounds__(256, 2)
__global__ void score_kernel(const _Float16* __restrict__ Xh,
                             const _Float16* __restrict__ Dh,
                             const int* __restrict__ mask,
                             _Float16* __restrict__ E,
                             float* __restrict__ lsum,
                             _Float16* __restrict__ Tmax) {   // [8192 tokens][128 tiles]
  __shared__ _Float16 lds[17408];          // dbuf staging 2x(As 4096 + Bs 4096); epilogue 128x136
  const int tid  = threadIdx.x;
  const int lane = tid & 63;
  const int wave = tid >> 6;
  const int wm = wave >> 1, wn = wave & 1;
  const int m0 = blockIdx.y * 128;         // token tile
  const int n0 = blockIdx.x * 128;         // atom tile

  const int frow = lane & 15;
  const int fkc  = lane >> 4;

  f32x4 acc[4][4] = {};

  stage_ab(Xh, Dh, lds, lds + 4096, m0, n0, DMODEL, 0, tid);
  int cur = 0;
  for (int it = 0; it < DMODEL / 32; ++it) {
    __syncthreads();                       // drains vmcnt: buf[cur] ready (issued 1 compute ago)
    if (it + 1 < DMODEL / 32)
      stage_ab(Xh, Dh, lds + (cur ^ 1) * 8192, lds + (cur ^ 1) * 8192 + 4096,
               m0, n0, DMODEL, (it + 1) * 32, tid);
    _Float16* As = lds + cur * 8192;
    _Float16* Bs = As + 4096;
    half8 af[4], bf[4];
    #pragma unroll
    for (int i = 0; i < 4; i++) {
      int ar = wm * 64 + i * 16 + frow;
      int br = wn * 64 + i * 16 + frow;
      af[i] = *(const half8*)&As[ar * 32 + (fkc ^ ((ar >> 1) & 3)) * 8];
      bf[i] = *(const half8*)&Bs[br * 32 + (fkc ^ ((br >> 1) & 3)) * 8];
    }
    #pragma unroll
    for (int i = 0; i < 4; i++)
      #pragma unroll
      for (int j = 0; j < 4; j++)
        acc[i][j] = __builtin_amdgcn_mfma_f32_16x16x32_f16(af[i], bf[j], acc[i][j], 0, 0, 0);
    cur ^= 1;
  }

  __syncthreads();
  // epilogue: C/D layout col=lane&15, row=(lane>>4)*4+reg. mask+exp -> LDS (stride 136) -> stores.
  const int cr = (lane >> 4) * 4;
  const int cc = lane & 15;
  #pragma unroll
  for (int i = 0; i < 4; i++) {
    #pragma unroll
    for (int j = 0; j < 4; j++) {
      #pragma unroll
      for (int r = 0; r < 4; r++) {
        int lr = wm * 64 + i * 16 + cr + r;
        int lc = wn * 64 + j * 16 + cc;
        int mk = mask[(size_t)(m0 + lr) * NATOM + (n0 + lc)];
        float e = mk ? __expf(acc[i][j][r]) : 0.0f;   // scores bounded |s|<=11: no max-subtract
        lds[lr * 136 + lc] = (_Float16)e;
      }
    }
  }
  __syncthreads();
  // coalesced E store
  #pragma unroll
  for (int i = 0; i < 8; i++) {
    int chunk = i * 256 + tid;
    int r  = chunk >> 4;
    int c8 = (chunk & 15) * 8;
    *(half8*)&E[(size_t)(m0 + r) * NATOM + n0 + c8] = *(const half8*)&lds[r * 136 + c8];
  }
  // per-row partial sum (-> atomic lsum) and tile max (-> Tmax, token-major)
  {
    int r = tid >> 1, h = tid & 1;
    const _Float16* rowp = &lds[r * 136 + h * 64];
    float s = 0.0f, m = 0.0f;
    #pragma unroll
    for (int i = 0; i < 8; i++) {
      half8 v = *(const half8*)&rowp[i * 8];
      #pragma unroll
      for (int j = 0; j < 8; j++) { float f = (float)v[j]; s += f; m = fmaxf(m, f); }
    }
    s += __shfl_xor(s, 1, 64);
    m = fmaxf(m, __shfl_xor(m, 1, 64));
    if (h == 0) {
      atomicAdd(&lsum[m0 + r], s);
      Tmax[(size_t)(m0 + r) * 128 + blockIdx.x] = (_Float16)m;   // token-major
    }
  }
}

// ---------------- kernel 2: sparse argmax scan (1 wave / token, 4 tokens / block) ----------------
// Tmax is token-major: each wave reads two contiguous 128B segments (was 128 scattered
// cache lines). Only tiles with max >= 0.98*gmax get their 128 E values re-read; any
// true-winner candidate satisfies the 0.98 margin (84 sigma of fp16-GEMM error), then
// exact fp64 re-evaluation, ties -> lowest index (np.argmax). Single-wave scope: CDNA
// wave64 is lockstep, LDS writes are visible in program order -> no barriers needed.
__global__ void scan_lite(const _Float16* __restrict__ E,
                          const _Float16* __restrict__ Tmax,   // [8192][128]
                          const float* __restrict__ x,
                          const float* __restrict__ dict,
                          float* __restrict__ argout) {
  const int wv   = threadIdx.x >> 6;       // 0..3
  const int lane = threadIdx.x & 63;
  const int t = blockIdx.x * 4 + wv;

  __shared__ int    cnt[4];
  __shared__ int    cand[4][32];
  __shared__ double csc[4][32];
  if (lane == 0) cnt[wv] = 0;

  const _Float16* tm = Tmax + (size_t)t * 128;
  float m0 = (float)tm[lane];
  float m1 = (float)tm[64 + lane];
  float mx = fmaxf(m0, m1);
  #pragma unroll
  for (int off = 32; off > 0; off >>= 1) mx = fmaxf(mx, __shfl_xor(mx, off, 64));

  if (mx > 0.0f) {
    float thr = 0.98f * mx;
    unsigned long long q0 = __ballot(m0 >= thr);
    unsigned long long q1 = __ballot(m1 >= thr);
    while (q0 | q1) {
      int tile;
      if (q0) { tile = __ffsll(q0) - 1; q0 &= q0 - 1; }
      else    { tile = 64 + __ffsll(q1) - 1; q1 &= q1 - 1; }
      const _Float16* ep = E + (size_t)t * NATOM + tile * 128;
      float e0 = (float)ep[lane], e1 = (float)ep[64 + lane];
      if (e0 >= thr) { int p = atomicAdd(&cnt[wv], 1); if (p < 32) cand[wv][p] = tile * 128 + lane; }
      if (e1 >= thr) { int p = atomicAdd(&cnt[wv], 1); if (p < 32) cand[wv][p] = tile * 128 + 64 + lane; }
    }
  }
  int nc = min(cnt[wv], 32);
  const float* xr = x + (size_t)t * DMODEL;
  for (int c = 0; c < nc; c++) {
    const float* dr = dict + (size_t)cand[wv][c] * DMODEL;
    double a = 0.0;
    #pragma unroll
    for (int i = 0; i < 16; i++) {
      int d = lane + i * 64;
      a += (double)xr[d] * (double)dr[d];
    }
    #pragma unroll
    for (int off = 32; off > 0; off >>= 1) a += __shfl_down(a, off, 64);
    if (lane == 0) csc[wv][c] = a;
  }
  if (lane == 0) {
    int best = 0;                          // all-masked -> np.argmax of equal values = 0
    if (nc > 0) {
      double bs = -1e300;
      best = NATOM;
      for (int c = 0; c < nc; c++)
        if (csc[wv][c] > bs || (csc[wv][c] == bs && cand[wv][c] < best)) { bs = csc[wv][c]; best = cand[wv][c]; }
    }
    argout[t] = (float)best;               // harness reads d_out as float32
  }
}

// ---------------- kernel 3: recon = (E @ dT^T) / l ----------------
// ROUND-1 VERBATIM (best measured ~422 us): M128 x N128, grid 512 flat with XCD-chunked
// mapping, quad-buffered counted-vmcnt loop (vmcnt(8) steady state), K = 16384 (512 tiles).
__launch_bounds__(256, 2)
__global__ void recon_kernel(const _Float16* __restrict__ E,
                             const _Float16* __restrict__ DT,
                             const float* __restrict__ lsum,
                             float* __restrict__ out) {
  __shared__ _Float16 lds[32768];          // 4 bufs x (As 128x32 + Bs 128x32)
  const int tid  = threadIdx.x;
  const int lane = tid & 63;
  const int wave = tid >> 6;
  const int wm = wave >> 1, wn = wave & 1;
  const int swz = (blockIdx.x & 7) * 64 + (blockIdx.x >> 3);
  const int n0 = (swz & 7) * 128;          // d_model tile
  const int m0 = (swz >> 3) * 128;         // token tile

  const int frow = lane & 15;
  const int fkc  = lane >> 4;

  f32x4 acc[4][4] = {};

  stage_ab(E, DT, lds,         lds + 4096,  m0, n0, NATOM, 0,  tid);
  stage_ab(E, DT, lds + 8192,  lds + 12288, m0, n0, NATOM, 32, tid);
  stage_ab(E, DT, lds + 16384, lds + 20480, m0, n0, NATOM, 64, tid);

  for (int t = 0; t < 512; ++t) {
    if (t < 510)       asm volatile("s_waitcnt vmcnt(8)" ::: "memory");
    else if (t == 510) asm volatile("s_waitcnt vmcnt(4)" ::: "memory");
    else               asm volatile("s_waitcnt vmcnt(0)" ::: "memory");
    __builtin_amdgcn_s_barrier();
    __builtin_amdgcn_sched_barrier(0);
    const _Float16* As = lds + (t & 3) * 8192;
    const _Float16* Bs = As + 4096;
    half8 af[4], bf[4];
    #pragma unroll
    for (int i = 0; i < 4; i++) {
      int ar = wm * 64 + i * 16 + frow;
      int br = wn * 64 + i * 16 + frow;
      af[i] = *(const half8*)&As[ar * 32 + ((fkc ^ ((ar >> 1) & 3)) << 3)];
      bf[i] = *(const half8*)&Bs[br * 32 + ((fkc ^ ((br >> 1) & 3)) << 3)];
    }
    if (t + 3 < 512) {
      int b = (t + 3) & 3;
      stage_ab(E, DT, lds + b * 8192, lds + b * 8192 + 4096, m0, n0, NATOM, (t + 3) * 32, tid);
    }
    __builtin_amdgcn_s_setprio(1);
    #pragma unroll
    for (int i = 0; i < 4; i++)
      #pragma unroll
      for (int j = 0; j < 4; j++)
        acc[i][j] = __builtin_amdgcn_mfma_f32_16x16x32_f16(af[i], bf[j], acc[i][j], 0, 0, 0);
    __builtin_amdgcn_s_setprio(0);
    __builtin_amdgcn_sched_barrier(0);
  }

  const int cr = (lane >> 4) * 4;
  const int cc = lane & 15;
  #pragma unroll
  for (int i = 0; i < 4; i++) {
    #pragma unroll
    for (int r = 0; r < 4; r++) {
      int lr = wm * 64 + i * 16 + cr + r;
      float sc = 1.0f / lsum[m0 + lr];
      #pragma unroll
      for (int j = 0; j < 4; j++) {
        int lc = wn * 64 + j * 16 + cc;
        out[(size_t)(m0 + lr) * DMODEL + (n0 + lc)] = acc[i][j][r] * sc;
      }
    }
  }
}

extern "C" void kernel_launch(void* const* d_in, const int* in_sizes, int n_in,
                              void* d_out, int out_size, void* d_ws, size_t ws_size,
                              hipStream_t stream) {
  const float* x    = (const float*)d_in[0];
  const float* dict = (const float*)d_in[1];
  const int*   mask = (const int*)d_in[2];
  float* recon  = (float*)d_out;
  float* argout = recon + (size_t)NTOK * DMODEL;

  // workspace layout (336 MB + 32 KB — proven size)
  char* w = (char*)d_ws;
  _Float16* Xh = (_Float16*)(w);                                 // 16 MB  [8192,1024]
  _Float16* Dh = (_Float16*)(w + (size_t)16  * 1024 * 1024);     // 32 MB  [16384,1024]
  _Float16* DT = (_Float16*)(w + (size_t)48  * 1024 * 1024);     // 32 MB  [1024,16384]
  _Float16* E  = (_Float16*)(w + (size_t)80  * 1024 * 1024);     // 256 MB [8192,16384]
  float*  lsum = (float*)  (w + (size_t)336 * 1024 * 1024);      // 32 KB
  // Tmax (2 MB fp16, token-major [8192][128]) borrows the front of d_out's recon region;
  // scan_lite consumes it before recon_kernel overwrites the region (stream-serialized).
  _Float16* Tmax = (_Float16*)d_out;

  cvt_f32_f16<<<dim3(NTOK * DMODEL / 4 / 256), 256, 0, stream>>>(x, Xh, NTOK * DMODEL / 4);
  transpose_dict<<<dim3(NATOM / 64, DMODEL / 64), 256, 0, stream>>>(dict, Dh, DT);
  zero_lsum<<<dim3(NTOK / 256), 256, 0, stream>>>(lsum);
  score_kernel<<<dim3(NATOM / 128, NTOK / 128), 256, 0, stream>>>(Xh, Dh, mask, E, lsum, Tmax);
  scan_lite<<<dim3(NTOK / 4), 256, 0, stream>>>(E, Tmax, x, dict, argout);
  recon_kernel<<<dim3(512), 256, 0, stream>>>(E, DT, lsum, recon);
}

// Round 5
// 1378.870 us; speedup vs baseline: 1.1056x; 1.0343x over previous
//
#include <hip/hip_runtime.h>

#define NTOK   8192
#define DMODEL 1024
#define NATOM  16384

typedef _Float16 half8  __attribute__((ext_vector_type(8)));
typedef _Float16 half4_t __attribute__((ext_vector_type(4)));
typedef float    f32x4  __attribute__((ext_vector_type(4)));

// async global->LDS, 16B per lane; LDS dest is wave-uniform base + lane*16
#define GLOAD_LDS16(gsrc, ldst) \
  __builtin_amdgcn_global_load_lds((const __attribute__((address_space(1))) unsigned int*)(gsrc), \
                                   (__attribute__((address_space(3))) unsigned int*)(ldst), 16, 0, 0)

// ---------------- prep: fp32 -> fp16 (x only) ----------------
__global__ void cvt_f32_f16(const float* __restrict__ in, _Float16* __restrict__ out, int n4) {
  int i = blockIdx.x * 256 + threadIdx.x;
  if (i >= n4) return;
  float4 v = ((const float4*)in)[i];
  half4_t h;
  h[0] = (_Float16)v.x; h[1] = (_Float16)v.y; h[2] = (_Float16)v.z; h[3] = (_Float16)v.w;
  ((half4_t*)out)[i] = h;
}

// ---------------- prep: dict f32 -> Dh [16384,1024] f16 AND dT [1024,16384] f16 ----------------
__global__ void transpose_dict(const float* __restrict__ dict,
                               _Float16* __restrict__ Dh, _Float16* __restrict__ dT) {
  __shared__ _Float16 tile[64][68];
  int a0 = blockIdx.x * 64;   // atom tile
  int d0 = blockIdx.y * 64;   // dim tile
  int tid = threadIdx.x;
  int c = tid & 63;
  int r0 = tid >> 6;
  #pragma unroll
  for (int i = 0; i < 16; i++) {
    int r = r0 + i * 4;
    _Float16 h = (_Float16)dict[(size_t)(a0 + r) * DMODEL + d0 + c];
    tile[r][c] = h;
    Dh[(size_t)(a0 + r) * DMODEL + d0 + c] = h;
  }
  __syncthreads();
  #pragma unroll
  for (int i = 0; i < 16; i++) {
    int rd = r0 + i * 4;
    dT[(size_t)(d0 + rd) * NATOM + a0 + c] = tile[c][rd];
  }
}

__global__ void zero_lsum(float* __restrict__ lsum) {
  lsum[blockIdx.x * 256 + threadIdx.x] = 0.0f;
}

// 128-row staging helper for recon (proven): 128 rows x 32 k, XOR k-chunk swizzle
__device__ __forceinline__ void stage_ab(const _Float16* __restrict__ A,
                                         const _Float16* __restrict__ B,
                                         _Float16* As, _Float16* Bs,
                                         size_t arow0, size_t brow0, size_t ldk,
                                         int k0, int tid) {
  #pragma unroll
  for (int i = 0; i < 2; i++) {
    int L = tid + i * 256;               // 0..511 = 128 rows x 4 chunks
    int r = L >> 2, pc = L & 3;
    int c = pc ^ ((r >> 1) & 3);
    GLOAD_LDS16(A + (arow0 + r) * ldk + k0 + c * 8, As + (size_t)L * 8);
    GLOAD_LDS16(B + (brow0 + r) * ldk + k0 + c * 8, Bs + (size_t)L * 8);
  }
}

// score staging: one "item" = one k-slot (32 k) of A or B for a 256-row tile = 16 KB,
// lane-linear LDS dest (L2 stride 16B), XOR k-chunk swizzle folded into the GLOBAL source
// address. 2 gload_lds per thread per item (512 threads).
__device__ __forceinline__ void stage_item(const _Float16* __restrict__ src, int row0,
                                           int kt, int s, _Float16* dst, int tid) {
  #pragma unroll
  for (int i = 0; i < 2; i++) {
    int L2 = tid + i * 512;              // 0..1023 = 256 rows x 4 chunks
    int r = L2 >> 2, q = L2 & 3;
    int c = s * 4 + (q ^ (r & 3));       // source k-chunk
    GLOAD_LDS16(src + (size_t)(row0 + r) * DMODEL + kt * 64 + c * 8, dst + (size_t)L2 * 8);
  }
}

// ---------------- kernel 1: E = mask ? exp(x @ dict^T) : 0, + row-tile sum/max ----------------
// 256x256 tile, BK=64, 8 waves (2m x 4n), fine-phase schedule (4 phases per K-tile):
// phase p (s=p>>1, mh=p&1) = {ds_read frags, stage 1 item (2 gload_lds), lgkmcnt(0)+SB(0),
// setprio(1), 16 MFMA, setprio(0), [vmcnt(4) at odd phases], s_barrier}.
// LDS k-slot-major per buffer: A_s0|A_s1|B_s0|B_s1 contiguous 16KB items (m104-legal
// linear dest). Items staged 3-4 phases ahead of their deadline; main loop never drains
// vmcnt to 0. 2 buffers x 64KB = 128KB LDS, 1 block/CU (m201 configuration).
__launch_bounds__(512, 2)
__global__ void score_kernel(const _Float16* __restrict__ Xh,
                             const _Float16* __restrict__ Dh,
                             const int* __restrict__ mask,
                             _Float16* __restrict__ E,
                             float* __restrict__ lsum,
                             _Float16* __restrict__ Tmax) {   // [8192 tokens][128 tiles]
  __shared__ _Float16 lds[65536];          // 2 bufs x 32768; epilogue reuses 256x136
  const int tid  = threadIdx.x;
  const int lane = tid & 63;
  const int wave = tid >> 6;               // 0..7
  const int wm = wave >> 2;                // 0..1  (128 token rows each)
  const int wn = wave & 3;                 // 0..3  (64 atom cols each)
  const int m0 = blockIdx.y * 256;         // token tile
  const int n0 = blockIdx.x * 256;         // atom tile

  const int frow = lane & 15;
  const int fkc  = lane >> 4;              // k-chunk 0..3 within a 32-k slot

  f32x4 acc[8][4] = {};

  // fragment read offsets (elements): buffer halves A_s0 @0, A_s1 @8192, B_s0 @16384, B_s1 @24576
  #define AOFF(B_, S_, ROW_) ((B_) * 32768 + (S_) * 8192 + (((ROW_) << 2) + (fkc ^ ((ROW_) & 3))) * 8)
  #define BOFF(B_, S_, ROW_) ((B_) * 32768 + 16384 + (S_) * 8192 + (((ROW_) << 2) + (fkc ^ ((ROW_) & 3))) * 8)

  // prologue: stage kt0's 4 items (issue order: A_s0, B_s0, A_s1, B_s1)
  stage_item(Xh, m0, 0, 0, lds,         tid);
  stage_item(Dh, n0, 0, 0, lds + 16384, tid);
  stage_item(Xh, m0, 0, 1, lds + 8192,  tid);
  stage_item(Dh, n0, 0, 1, lds + 24576, tid);
  asm volatile("s_waitcnt vmcnt(4)" ::: "memory");   // s0 items resident; s1 still in flight
  __builtin_amdgcn_s_barrier();

  const int NKT = DMODEL / 64;             // 16
  for (int kt = 0; kt < NKT; ++kt) {
    const int b  = kt & 1;
    const int nb = b ^ 1;
    const bool more = (kt + 1 < NKT);
    half8 af[4], bf[4];

    // ---- phase 0: s=0, mh=0 ----
    #pragma unroll
    for (int i = 0; i < 4; i++) af[i] = *(const half8*)&lds[AOFF(b, 0, wm * 128 + i * 16 + frow)];
    #pragma unroll
    for (int j = 0; j < 4; j++) bf[j] = *(const half8*)&lds[BOFF(b, 0, wn * 64 + j * 16 + frow)];
    if (more) stage_item(Xh, m0, kt + 1, 0, lds + nb * 32768, tid);
    asm volatile("s_waitcnt lgkmcnt(0)" ::: "memory");
    __builtin_amdgcn_sched_barrier(0);
    __builtin_amdgcn_s_setprio(1);
    #pragma unroll
    for (int i = 0; i < 4; i++)
      #pragma unroll
      for (int j = 0; j < 4; j++)
        acc[i][j] = __builtin_amdgcn_mfma_f32_16x16x32_f16(af[i], bf[j], acc[i][j], 0, 0, 0);
    __builtin_amdgcn_s_setprio(0);
    __builtin_amdgcn_sched_barrier(0);
    __builtin_amdgcn_s_barrier();

    // ---- phase 1: s=0, mh=1 (reuse bf) ----
    #pragma unroll
    for (int i = 0; i < 4; i++) af[i] = *(const half8*)&lds[AOFF(b, 0, wm * 128 + 64 + i * 16 + frow)];
    if (more) stage_item(Dh, n0, kt + 1, 0, lds + nb * 32768 + 16384, tid);
    asm volatile("s_waitcnt lgkmcnt(0)" ::: "memory");
    __builtin_amdgcn_sched_barrier(0);
    __builtin_amdgcn_s_setprio(1);
    #pragma unroll
    for (int i = 0; i < 4; i++)
      #pragma unroll
      for (int j = 0; j < 4; j++)
        acc[4 + i][j] = __builtin_amdgcn_mfma_f32_16x16x32_f16(af[i], bf[j], acc[4 + i][j], 0, 0, 0);
    __builtin_amdgcn_s_setprio(0);
    __builtin_amdgcn_sched_barrier(0);
    if (more) asm volatile("s_waitcnt vmcnt(4)" ::: "memory");   // retire this buf's s1 items
    else      asm volatile("s_waitcnt vmcnt(0)" ::: "memory");
    __builtin_amdgcn_s_barrier();

    // ---- phase 2: s=1, mh=0 ----
    #pragma unroll
    for (int i = 0; i < 4; i++) af[i] = *(const half8*)&lds[AOFF(b, 1, wm * 128 + i * 16 + frow)];
    #pragma unroll
    for (int j = 0; j < 4; j++) bf[j] = *(const half8*)&lds[BOFF(b, 1, wn * 64 + j * 16 + frow)];
    if (more) stage_item(Xh, m0, kt + 1, 1, lds + nb * 32768 + 8192, tid);
    asm volatile("s_waitcnt lgkmcnt(0)" ::: "memory");
    __builtin_amdgcn_sched_barrier(0);
    __builtin_amdgcn_s_setprio(1);
    #pragma unroll
    for (int i = 0; i < 4; i++)
      #pragma unroll
      for (int j = 0; j < 4; j++)
        acc[i][j] = __builtin_amdgcn_mfma_f32_16x16x32_f16(af[i], bf[j], acc[i][j], 0, 0, 0);
    __builtin_amdgcn_s_setprio(0);
    __builtin_amdgcn_sched_barrier(0);
    __builtin_amdgcn_s_barrier();

    // ---- phase 3: s=1, mh=1 (reuse bf) ----
    #pragma unroll
    for (int i = 0; i < 4; i++) af[i] = *(const half8*)&lds[AOFF(b, 1, wm * 128 + 64 + i * 16 + frow)];
    if (more) stage_item(Dh, n0, kt + 1, 1, lds + nb * 32768 + 24576, tid);
    asm volatile("s_waitcnt lgkmcnt(0)" ::: "memory");
    __builtin_amdgcn_sched_barrier(0);
    __builtin_amdgcn_s_setprio(1);
    #pragma unroll
    for (int i = 0; i < 4; i++)
      #pragma unroll
      for (int j = 0; j < 4; j++)
        acc[4 + i][j] = __builtin_amdgcn_mfma_f32_16x16x32_f16(af[i], bf[j], acc[4 + i][j], 0, 0, 0);
    __builtin_amdgcn_s_setprio(0);
    __builtin_amdgcn_sched_barrier(0);
    if (more) asm volatile("s_waitcnt vmcnt(4)" ::: "memory");   // retire next buf's s0 items
    __builtin_amdgcn_s_barrier();
  }
  #undef AOFF
  #undef BOFF

  // epilogue in two 128-col passes (pass h = scan tile bx*2+h). C/D layout:
  // token lr = wm*128 + i*16 + (lane>>4)*4 + r ; atom lc = wn*64 + j*16 + (lane&15).
  const int cr = (lane >> 4) * 4;
  const int cc = lane & 15;
  const int rr = tid >> 1, hh = tid & 1;   // reduce mapping: 2 threads/row
  float s_acc = 0.0f;
  #pragma unroll
  for (int h = 0; h < 2; h++) {
    if ((wn >> 1) == h) {
      #pragma unroll
      for (int i = 0; i < 8; i++) {
        #pragma unroll
        for (int j = 0; j < 4; j++) {
          #pragma unroll
          for (int r = 0; r < 4; r++) {
            int lr = wm * 128 + i * 16 + cr + r;
            int lc = (wn & 1) * 64 + j * 16 + cc;          // 0..127 within the half
            int mk = mask[(size_t)(m0 + lr) * NATOM + n0 + h * 128 + lc];
            float e = mk ? __expf(acc[i][j][r]) : 0.0f;    // |s|<=11: exp fits fp16
            lds[lr * 136 + lc] = (_Float16)e;
          }
        }
      }
    }
    __builtin_amdgcn_s_barrier();
    // coalesced E store for this half: 256 rows x 128 cols
    #pragma unroll
    for (int i = 0; i < 8; i++) {
      int chunk = i * 512 + tid;
      int r  = chunk >> 4;
      int c8 = (chunk & 15) * 8;
      *(half8*)&E[(size_t)(m0 + r) * NATOM + n0 + h * 128 + c8] = *(const half8*)&lds[r * 136 + c8];
    }
    // per-row partial sum (accumulated across passes) and per-half tile max
    {
      const _Float16* rowp = &lds[rr * 136 + hh * 64];
      float s = 0.0f, m = 0.0f;
      #pragma unroll
      for (int i = 0; i < 8; i++) {
        half8 v = *(const half8*)&rowp[i * 8];
        #pragma unroll
        for (int j = 0; j < 8; j++) { float f = (float)v[j]; s += f; m = fmaxf(m, f); }
      }
      s += __shfl_xor(s, 1, 64);
      m = fmaxf(m, __shfl_xor(m, 1, 64));
      if (hh == 0) {
        s_acc += s;
        Tmax[(size_t)(m0 + rr) * 128 + blockIdx.x * 2 + h] = (_Float16)m;  // token-major
      }
    }
    __builtin_amdgcn_s_barrier();
  }
  if (hh == 0) atomicAdd(&lsum[m0 + rr], s_acc);
}

// ---------------- kernel 2: sparse argmax scan (1 wave / token, 4 tokens / block) ----------------
// Tmax token-major: two contiguous 128B reads/wave. Tiles with max >= 0.98*gmax get their
// 128 E values re-read (margin = 84 sigma of fp16-GEMM error), exact fp64 re-eval,
// ties -> lowest index. Single-wave scope: lockstep, no barriers.
__global__ void scan_lite(const _Float16* __restrict__ E,
                          const _Float16* __restrict__ Tmax,   // [8192][128]
                          const float* __restrict__ x,
                          const float* __restrict__ dict,
                          float* __restrict__ argout) {
  const int wv   = threadIdx.x >> 6;       // 0..3
  const int lane = threadIdx.x & 63;
  const int t = blockIdx.x * 4 + wv;

  __shared__ int    cnt[4];
  __shared__ int    cand[4][32];
  __shared__ double csc[4][32];
  if (lane == 0) cnt[wv] = 0;

  const _Float16* tm = Tmax + (size_t)t * 128;
  float m0 = (float)tm[lane];
  float m1 = (float)tm[64 + lane];
  float mx = fmaxf(m0, m1);
  #pragma unroll
  for (int off = 32; off > 0; off >>= 1) mx = fmaxf(mx, __shfl_xor(mx, off, 64));

  if (mx > 0.0f) {
    float thr = 0.98f * mx;
    unsigned long long q0 = __ballot(m0 >= thr);
    unsigned long long q1 = __ballot(m1 >= thr);
    while (q0 | q1) {
      int tile;
      if (q0) { tile = __ffsll(q0) - 1; q0 &= q0 - 1; }
      else    { tile = 64 + __ffsll(q1) - 1; q1 &= q1 - 1; }
      const _Float16* ep = E + (size_t)t * NATOM + tile * 128;
      float e0 = (float)ep[lane], e1 = (float)ep[64 + lane];
      if (e0 >= thr) { int p = atomicAdd(&cnt[wv], 1); if (p < 32) cand[wv][p] = tile * 128 + lane; }
      if (e1 >= thr) { int p = atomicAdd(&cnt[wv], 1); if (p < 32) cand[wv][p] = tile * 128 + 64 + lane; }
    }
  }
  int nc = min(cnt[wv], 32);
  const float* xr = x + (size_t)t * DMODEL;
  for (int c = 0; c < nc; c++) {
    const float* dr = dict + (size_t)cand[wv][c] * DMODEL;
    double a = 0.0;
    #pragma unroll
    for (int i = 0; i < 16; i++) {
      int d = lane + i * 64;
      a += (double)xr[d] * (double)dr[d];
    }
    #pragma unroll
    for (int off = 32; off > 0; off >>= 1) a += __shfl_down(a, off, 64);
    if (lane == 0) csc[wv][c] = a;
  }
  if (lane == 0) {
    int best = 0;                          // all-masked -> np.argmax of equal values = 0
    if (nc > 0) {
      double bs = -1e300;
      best = NATOM;
      for (int c = 0; c < nc; c++)
        if (csc[wv][c] > bs || (csc[wv][c] == bs && cand[wv][c] < best)) { bs = csc[wv][c]; best = cand[wv][c]; }
    }
    argout[t] = (float)best;               // harness reads d_out as float32
  }
}

// ---------------- kernel 3: recon = (E @ dT^T) / l ----------------
// ROUND-1 FORM (best measured ~430 us): M128 x N128, grid 512 flat with XCD-chunked
// mapping, quad-buffered counted-vmcnt loop (vmcnt(8) steady state), K = 16384 (512 tiles).
__launch_bounds__(256, 2)
__global__ void recon_kernel(const _Float16* __restrict__ E,
                             const _Float16* __restrict__ DT,
                             const float* __restrict__ lsum,
                             float* __restrict__ out) {
  __shared__ _Float16 lds[32768];          // 4 bufs x (As 128x32 + Bs 128x32)
  const int tid  = threadIdx.x;
  const int lane = tid & 63;
  const int wave = tid >> 6;
  const int wm = wave >> 1, wn = wave & 1;
  const int swz = (blockIdx.x & 7) * 64 + (blockIdx.x >> 3);
  const int n0 = (swz & 7) * 128;          // d_model tile
  const int m0 = (swz >> 3) * 128;         // token tile

  const int frow = lane & 15;
  const int fkc  = lane >> 4;

  f32x4 acc[4][4] = {};

  stage_ab(E, DT, lds,         lds + 4096,  m0, n0, NATOM, 0,  tid);
  stage_ab(E, DT, lds + 8192,  lds + 12288, m0, n0, NATOM, 32, tid);
  stage_ab(E, DT, lds + 16384, lds + 20480, m0, n0, NATOM, 64, tid);

  for (int t = 0; t < 512; ++t) {
    if (t < 510)       asm volatile("s_waitcnt vmcnt(8)" ::: "memory");
    else if (t == 510) asm volatile("s_waitcnt vmcnt(4)" ::: "memory");
    else               asm volatile("s_waitcnt vmcnt(0)" ::: "memory");
    __builtin_amdgcn_s_barrier();
    __builtin_amdgcn_sched_barrier(0);
    const _Float16* As = lds + (t & 3) * 8192;
    const _Float16* Bs = As + 4096;
    half8 af[4], bf[4];
    #pragma unroll
    for (int i = 0; i < 4; i++) {
      int ar = wm * 64 + i * 16 + frow;
      int br = wn * 64 + i * 16 + frow;
      af[i] = *(const half8*)&As[ar * 32 + ((fkc ^ ((ar >> 1) & 3)) << 3)];
      bf[i] = *(const half8*)&Bs[br * 32 + ((fkc ^ ((br >> 1) & 3)) << 3)];
    }
    if (t + 3 < 512) {
      int b = (t + 3) & 3;
      stage_ab(E, DT, lds + b * 8192, lds + b * 8192 + 4096, m0, n0, NATOM, (t + 3) * 32, tid);
    }
    __builtin_amdgcn_s_setprio(1);
    #pragma unroll
    for (int i = 0; i < 4; i++)
      #pragma unroll
      for (int j = 0; j < 4; j++)
        acc[i][j] = __builtin_amdgcn_mfma_f32_16x16x32_f16(af[i], bf[j], acc[i][j], 0, 0, 0);
    __builtin_amdgcn_s_setprio(0);
    __builtin_amdgcn_sched_barrier(0);
  }

  const int cr = (lane >> 4) * 4;
  const int cc = lane & 15;
  #pragma unroll
  for (int i = 0; i < 4; i++) {
    #pragma unroll
    for (int r = 0; r < 4; r++) {
      int lr = wm * 64 + i * 16 + cr + r;
      float sc = 1.0f / lsum[m0 + lr];
      #pragma unroll
      for (int j = 0; j < 4; j++) {
        int lc = wn * 64 + j * 16 + cc;
        out[(size_t)(m0 + lr) * DMODEL + (n0 + lc)] = acc[i][j][r] * sc;
      }
    }
  }
}

extern "C" void kernel_launch(void* const* d_in, const int* in_sizes, int n_in,
                              void* d_out, int out_size, void* d_ws, size_t ws_size,
                              hipStream_t stream) {
  const float* x    = (const float*)d_in[0];
  const float* dict = (const float*)d_in[1];
  const int*   mask = (const int*)d_in[2];
  float* recon  = (float*)d_out;
  float* argout = recon + (size_t)NTOK * DMODEL;

  // workspace layout (336 MB + 32 KB — proven size)
  char* w = (char*)d_ws;
  _Float16* Xh = (_Float16*)(w);                                 // 16 MB  [8192,1024]
  _Float16* Dh = (_Float16*)(w + (size_t)16  * 1024 * 1024);     // 32 MB  [16384,1024]
  _Float16* DT = (_Float16*)(w + (size_t)48  * 1024 * 1024);     // 32 MB  [1024,16384]
  _Float16* E  = (_Float16*)(w + (size_t)80  * 1024 * 1024);     // 256 MB [8192,16384]
  float*  lsum = (float*)  (w + (size_t)336 * 1024 * 1024);      // 32 KB
  // Tmax (2 MB fp16, token-major [8192][128]) borrows the front of d_out's recon region;
  // scan_lite consumes it before recon_kernel overwrites the region (stream-serialized).
  _Float16* Tmax = (_Float16*)d_out;

  cvt_f32_f16<<<dim3(NTOK * DMODEL / 4 / 256), 256, 0, stream>>>(x, Xh, NTOK * DMODEL / 4);
  transpose_dict<<<dim3(NATOM / 64, DMODEL / 64), 256, 0, stream>>>(dict, Dh, DT);
  zero_lsum<<<dim3(NTOK / 256), 256, 0, stream>>>(lsum);
  score_kernel<<<dim3(NATOM / 256, NTOK / 256), 512, 0, stream>>>(Xh, Dh, mask, E, lsum, Tmax);
  scan_lite<<<dim3(NTOK / 4), 256, 0, stream>>>(E, Tmax, x, dict, argout);
  recon_kernel<<<dim3(512), 256, 0, stream>>>(E, DT, lsum, recon);
}